// Round 1
// baseline (192.459 us; speedup 1.0000x reference)
//
#include <hip/hip_runtime.h>
#include <hip/hip_fp16.h>
#include <math.h>

// Problem constants
#define BB 4
#define HH 48
#define WW 48
#define DD 64
#define CH 46
#define CWp 46
#define CC (CH*CWp)      // 2116 (true column count, for softmax stats)
#define KK 576           // 9*64
#define HWp (HH*WW)      // 2304
#define PW 50            // zero-padded field width
#define PP (PW*PW)       // 2500 padded pixels

// slot space: j padded per-row 46->48 -> K width 2208 = 69*32 (dummies are zero)
#define SLOTW 48
#define NSLOT 2208
#define NGRP 276         // 2208/8 groups of 8 slots
#define KPAD NSLOT       // row stride of CA & p1t
#define KSPLIT0 1120     // 35*32; split1 = [1120,2208) = 34 iters
#define QW 2304          // Q row width (v-domain = 48*48)
#define QROWS 2500       // Q rows (u-domain = 50*50)

typedef __attribute__((ext_vector_type(8))) short short8;
typedef __attribute__((ext_vector_type(4))) float float4v;

// ---------- workspace layout (byte offsets, all 16B-aligned) ----------
#define OFFB_GPAD  ((size_t)0)            // bf16 [B][2500][64]    1,280,000 B
#define OFFB_BGPAD ((size_t)1280000)      // bf16 [B][2500][64]    1,280,000 B
#define OFFB_E     ((size_t)2560000)      // f32  [B][2304]           36,864 B
#define OFFB_K1D   ((size_t)2596864)      // f32  [B][2208]           35,328 B
#define OFFB_P1T   ((size_t)2632192)      // bf16 [B][576][2208]  10,174,464 B
#define OFFB_S     ((size_t)12806656)     // bf16 CA [B][HW][2208] 40,697,856 B
#define OFFB_AGG0  ((size_t)53504512)     // fp16 [B][HW][576]    10,616,832 B
#define OFFB_AGG1  ((size_t)64121344)     // fp16 [B][HW][576]    10,616,832 B
#define OFFB_Q     ((size_t)74738176)     // fp16 [B][2500][2304] 46,080,000 B
// total 120,818,176 B (fill evidence: ws allocation is 256 MiB)

// ---------- helpers ----------
__device__ __forceinline__ ushort f2bf(float x) {
    unsigned u = __float_as_uint(x);
    return (ushort)((u + 0x7FFFu + ((u >> 16) & 1u)) >> 16);
}

__device__ __forceinline__ float waveReduceSum(float x) {
#pragma unroll
    for (int o = 32; o > 0; o >>= 1) x += __shfl_down(x, o, 64);
    return x;
}

// 5-wave block reduce (for 320-thread qrowsoft)
__device__ __forceinline__ float blockReduce5(float x, float* sm) {
#pragma unroll
    for (int o = 32; o > 0; o >>= 1) x += __shfl_down(x, o, 64);
    int lane = threadIdx.x & 63, w = threadIdx.x >> 6;
    __syncthreads();
    if (lane == 0) sm[w] = x;
    __syncthreads();
    return sm[0] + sm[1] + sm[2] + sm[3] + sm[4];
}

// fast tanh via hardware exp: tanh(z) = 1 - 2/(e^{2z}+1)
__device__ __forceinline__ float fast_tanh(float z) {
    float e = __expf(2.f * z);
    return 1.f - 2.f / (e + 1.f);
}

// async 16B global->LDS (wave-uniform LDS base + lane*16)
typedef __attribute__((address_space(3))) void lds_void_t;
typedef __attribute__((address_space(1))) void gmem_void_t;
__device__ __forceinline__ void gld16(const ushort* g, ushort* lds) {
    __builtin_amdgcn_global_load_lds((gmem_void_t*)g, (lds_void_t*)lds, 16, 0, 0);
}

// ---------- build padded fields: gpad = bf16(g), bgpad = bf16(g*mask), e = sum_c bg^2 ----------
__global__ __launch_bounds__(256) void build_pads(const float* __restrict__ g,
                                                  const float* __restrict__ mask,
                                                  ushort* __restrict__ gpad,
                                                  ushort* __restrict__ bgpad,
                                                  float* __restrict__ e) {
    int w = threadIdx.x >> 6, c = threadIdx.x & 63;
    int q4 = blockIdx.x * 4 + w;         // [0, B*2500)
    int b = q4 / PP, q = q4 % PP;
    int yp = q / PW, xp = q % PW;
    size_t o = (size_t)q4 * DD + c;
    if (yp >= 1 && yp <= HH && xp >= 1 && xp <= WW) {
        int pix = (yp - 1) * WW + (xp - 1);
        float gv = g[((size_t)b * HWp + pix) * DD + c];
        float m  = mask[(size_t)b * HWp + pix];
        float bgv = gv * m;
        gpad[o]  = f2bf(gv);
        bgpad[o] = f2bf(bgv);
        float ss = waveReduceSum(bgv * bgv);
        if (c == 0) e[b * HWp + pix] = ss;
    } else {
        gpad[o] = 0;
        bgpad[o] = 0;
    }
}

// ---------- p1t via LDS-tiled transpose from bgpad (slot space, + k1d) ----------
__global__ __launch_bounds__(256) void build_p1t(const ushort* __restrict__ bgpad,
                                                 const float* __restrict__ e,
                                                 ushort* __restrict__ p1t,
                                                 float* __restrict__ k1d) {
    int d9 = blockIdx.y, b = blockIdx.z;
    int t = threadIdx.x;
    if (blockIdx.x == 35) {
        int jg = (b * 9 + d9) * 256 + t;         // [0, 9216)
        if (jg < BB * NSLOT) {
            int bb = jg / NSLOT, st = jg - bb * NSLOT;
            int jy = st / SLOTW, jx = st - jy * SLOTW;   // jy <= 45 here
            float s = 0.f;
            if (jx < CWp) {
                const float* eb = e + bb * HWp + jy * WW + jx;
#pragma unroll
                for (int ddy = 0; ddy < 3; ddy++)
#pragma unroll
                    for (int ddx = 0; ddx < 3; ddx++) s += eb[ddy * WW + ddx];
            }
            k1d[jg] = s;
        }
        return;
    }
    __shared__ ushort T[64 * 65];
    int jt = blockIdx.x;                 // 0..34 (35*64 = 2240 >= 2208)
    int dy = d9 / 3, dx = d9 - dy * 3;
    const ushort* src = bgpad + (size_t)b * PP * DD;
    int lr = t >> 3, c8 = (t & 7) * 8;
#pragma unroll
    for (int pass = 0; pass < 2; pass++) {
        int r = lr + pass * 32;
        int st = jt * 64 + r;
        int jy = st / SLOTW, jx = st - jy * SLOTW;
        uint4 d = make_uint4(0, 0, 0, 0);
        if (jx < CWp && jy < CWp)
            d = *(const uint4*)(src + (size_t)((jy + dy + 1) * PW + (jx + dx + 1)) * DD + c8);
        ushort tmp[8];
        *(uint4*)tmp = d;
#pragma unroll
        for (int u = 0; u < 8; u++) T[r * 65 + c8 + u] = tmp[u];
    }
    __syncthreads();
#pragma unroll
    for (int pass = 0; pass < 2; pass++) {
        int c = lr + pass * 32;
        int j8 = (t & 7) * 8;
        int col0 = jt * 64 + j8;
        ushort tmp[8];
#pragma unroll
        for (int u = 0; u < 8; u++) tmp[u] = T[(j8 + u) * 65 + c];
        if (col0 < NSLOT)
            *(uint4*)(p1t + ((size_t)b * KK + d9 * 64 + c) * NSLOT + col0) = *(const uint4*)tmp;
    }
}

// ---------- Q-gemm: Q[u,v] = sum_d gpad[u,d]*bg[v,d], K=64, fp16 out ----------
// CS[m,j] = sum_{s in 3x3} Q[u(m)+s_u, v(j)+s_v] (diagonal box-sum, done in qrowsoft).
// Same staging/swizzle as the proven gemm1; 20 u-tiles x 18 v-tiles x 4 b = 1440 blocks.
__global__ __launch_bounds__(256) void qgemm(const ushort* __restrict__ gpad,
                                             const ushort* __restrict__ bgpad,
                                             __half* __restrict__ Qout) {
    __shared__ ushort As[2 * 4096];
    __shared__ ushort Bs[2 * 4096];
    int i0 = blockIdx.x;
    int b = (i0 & 7) >> 1;                    // batch pinned to XCD pair
    int tile = ((i0 >> 3) << 1) | (i0 & 1);   // 0..359, bijective
    int ty = tile / 18, tx = tile - ty * 18;
    int m0 = ty * 128, n0 = tx * 128;
    const ushort* Ag = gpad + (size_t)b * PP * DD;
    const ushort* Bg = bgpad + (size_t)b * PP * DD;

    int tid = threadIdx.x;
    int l = tid & 63, w = tid >> 6;
    int quad = l >> 4, l15 = l & 15;
    int sw8 = (l15 >> 1) & 3;
    int wm = (w >> 1) * 64, wn = (w & 1) * 64;
    int rowInC = l >> 2;
    int cSw = (l & 3) ^ ((l >> 3) & 3);

    // stage both K-halves up front (K=64 total)
#pragma unroll
    for (int i = 0; i < 2; i++) {
        int rg = w * 2 + i;
        int r = rg * 16 + rowInC;
        int u = m0 + r; if (u > QROWS - 1) u = QROWS - 1;  // clamp; store-guarded
        int n = n0 + r;                                     // < 2304 always
        int vy = n / 48, vx = n - vy * 48;
        int baseA = u * DD + cSw * 8;
        int baseB = ((vy + 1) * PW + (vx + 1)) * DD + cSw * 8;
        gld16(Ag + baseA, As + rg * 512);
        gld16(Bg + baseB, Bs + rg * 512);
        gld16(Ag + baseA + 32, As + 4096 + rg * 512);
        gld16(Bg + baseB + 32, Bs + 4096 + rg * 512);
    }
    float4v acc[4][4];
#pragma unroll
    for (int i = 0; i < 4; i++)
#pragma unroll
        for (int j = 0; j < 4; j++) acc[i][j] = (float4v){0.f, 0.f, 0.f, 0.f};
    __syncthreads();
#pragma unroll
    for (int kb = 0; kb < 2; kb++) {
        const ushort* Ax = As + kb * 4096;
        const ushort* Bx = Bs + kb * 4096;
        short8 af[4], bf[4];
#pragma unroll
        for (int i = 0; i < 4; i++)
            af[i] = *(const short8*)&Ax[(wm + i * 16 + l15) * 32 + ((quad ^ sw8)) * 8];
#pragma unroll
        for (int j = 0; j < 4; j++)
            bf[j] = *(const short8*)&Bx[(wn + j * 16 + l15) * 32 + ((quad ^ sw8)) * 8];
#pragma unroll
        for (int i = 0; i < 4; i++)
#pragma unroll
            for (int j = 0; j < 4; j++)
                acc[i][j] = __builtin_amdgcn_mfma_f32_16x16x32_bf16(af[i], bf[j], acc[i][j], 0, 0, 0);
    }
    __half* C = Qout + (size_t)b * QROWS * QW;
#pragma unroll
    for (int i = 0; i < 4; i++) {
#pragma unroll
        for (int j = 0; j < 4; j++) {
            int n = n0 + wn + j * 16 + l15;
#pragma unroll
            for (int r = 0; r < 4; r++) {
                int m = m0 + wm + i * 16 + quad * 4 + r;
                if (m < QROWS) C[(size_t)m * QW + n] = __float2half(acc[i][j][r]);
            }
        }
    }
}

// ---------- 9-point diagonal gather: ds[u] = k1d - 2*CS for one 8-slot group ----------
__device__ __forceinline__ void gather9(const __half* __restrict__ qb2,
                                        const float* __restrict__ k1,
                                        int g, float (&ds)[8], int& slot0, int& vc) {
    int jy = g / 6;
    int jxb = (g - jy * 6) * 8;
    slot0 = jy * SLOTW + jxb;
    vc = (jxb == 40) ? 6 : 8;
    float cs[8] = {0.f, 0.f, 0.f, 0.f, 0.f, 0.f, 0.f, 0.f};
    constexpr int UO[9] = {0, 1, 2, 50, 51, 52, 100, 101, 102};   // u offsets (x50 raster)
    constexpr int VO[9] = {0, 1, 2, 48, 49, 50, 96, 97, 98};      // v offsets (x48 raster)
#pragma unroll
    for (int s = 0; s < 9; s++) {
        const __half* p = qb2 + (size_t)UO[s] * QW + slot0;
        if ((VO[s] & 1) == 0) {
            uint4 d = *(const uint4*)(p + VO[s]);       // 4B-aligned (slot0 even)
            const __half2* h2 = (const __half2*)&d;
#pragma unroll
            for (int k = 0; k < 4; k++) {
                float2 f = __half22float2(h2[k]);
                cs[2 * k] += f.x; cs[2 * k + 1] += f.y;
            }
        } else {
            uint4 d = *(const uint4*)(p + VO[s] - 1);   // covers halves [-1..6]
            uint e2 = *(const uint*)(p + VO[s] + 7);    // covers halves [7..8]
            uint wv[5] = {d.x, d.y, d.z, d.w, e2};
#pragma unroll
            for (int k = 0; k < 4; k++) {
                uint a = (wv[k] >> 16) | (wv[k + 1] << 16);   // v_alignbit pattern
                __half2 h2 = *(__half2*)&a;
                float2 f = __half22float2(h2);
                cs[2 * k] += f.x; cs[2 * k + 1] += f.y;
            }
        }
    }
    float4 ka = *(const float4*)(k1 + slot0);
    float4 kb = *(const float4*)(k1 + slot0 + 4);
    float kk[8] = {ka.x, ka.y, ka.z, ka.w, kb.x, kb.y, kb.z, kb.w};
#pragma unroll
    for (int u = 0; u < 8; u++) ds[u] = kk[u] - 2.f * cs[u];
}

// ---------- fused CS-box-sum + standardize + -50*tanh + softmax -> bf16 CA ----------
// 320 threads (5 waves): thread t owns 8-slot group t (t < 276), one pass, no 2x tail.
__global__ __launch_bounds__(320) void qrowsoft(const __half* __restrict__ Q,
                                                const float* __restrict__ k1d,
                                                ushort* __restrict__ CA) {
    __shared__ float sm[5];
    int i0 = blockIdx.x;
    int b = (i0 & 7) >> 1;                       // batch pinned to XCD pair (matches qgemm)
    int yx = ((i0 >> 3) << 1) | (i0 & 1);        // [0, 2304)
    int y = yx / WW, x = yx - y * WW;
    size_t row = (size_t)b * HWp + yx;
    const __half* qb2 = Q + ((size_t)b * QROWS + y * PW + x) * QW;
    const float* k1 = k1d + (size_t)b * NSLOT;
    ushort* wout = CA + row * (size_t)NSLOT;

    int t = threadIdx.x;
    bool act = (t < NGRP);
    int slot0 = 0, vc = 0;
    float ds[8] = {0.f, 0.f, 0.f, 0.f, 0.f, 0.f, 0.f, 0.f};
    if (act) gather9(qb2, k1, t, ds, slot0, vc);

    float sum = 0.f;
#pragma unroll
    for (int u = 0; u < 8; u++) if (u < vc) sum += ds[u];
    sum = blockReduce5(sum, sm);
    float mu = sum / (float)CC;

    float vs = 0.f;
#pragma unroll
    for (int u = 0; u < 8; u++) if (u < vc) { float d = ds[u] - mu; vs += d * d; }
    vs = blockReduce5(vs, sm);
    float inv_sd = 1.f / sqrtf(vs / (float)CC);

    float es = 0.f;
#pragma unroll
    for (int u = 0; u < 8; u++) {
        ds[u] = (u < vc) ? __expf(-50.f * fast_tanh((ds[u] - mu) * inv_sd)) : 0.f;
        es += ds[u];
    }
    es = blockReduce5(es, sm);
    float invz = 1.f / es;

    if (act) {
        ushort o[8];
#pragma unroll
        for (int u = 0; u < 8; u++) o[u] = f2bf(ds[u] * invz);
        *(uint4*)(wout + slot0) = *(const uint4*)o;   // 16B-aligned (slot0 mult of 8)
    }
}

// ---------- MFMA GEMM core (NT), BK=32, double-buffered (for GEMM2) ----------
template <int NF, bool NMASK>
__device__ __forceinline__ void gemm_tile_db(const ushort* __restrict__ Ab,
                                             const ushort* __restrict__ Bb,
                                             int lda, int ldb, int kb, int ke,
                                             int Nrem,
                                             ushort* As, ushort* Bs,
                                             float4v (&acc)[4][NF]) {
    constexpr int NBI = NF / 2;
    constexpr int BBUF = 2048 * NBI;          // ushorts per B buffer
    int tid = threadIdx.x;
    int l = tid & 63, w = tid >> 6;
    int quad = l >> 4, l15 = l & 15;
    int sw8 = (l15 >> 1) & 3;
    int wm = (w >> 1) * 64, wn = (w & 1) * (NF * 16);
    int rowInC = l >> 2;
    int cSw = (l & 3) ^ ((l >> 3) & 3);

#pragma unroll
    for (int i = 0; i < 2; i++) {
        int rg = w * 2 + i;
        gld16(Ab + (size_t)(rg * 16 + rowInC) * lda + kb + cSw * 8, As + rg * 512);
    }
#pragma unroll
    for (int i = 0; i < NBI; i++) {
        int rg = w * NBI + i;
        int r = rg * 16 + rowInC;
        if (!NMASK || r < Nrem)
            gld16(Bb + (size_t)r * ldb + kb + cSw * 8, Bs + rg * 512);
    }

    int buf = 0;
    for (int k0 = kb; k0 < ke; k0 += 32) {
        __syncthreads();
        int nb = buf ^ 1;
        if (k0 + 32 < ke) {
#pragma unroll
            for (int i = 0; i < 2; i++) {
                int rg = w * 2 + i;
                gld16(Ab + (size_t)(rg * 16 + rowInC) * lda + (k0 + 32) + cSw * 8,
                      As + nb * 4096 + rg * 512);
            }
#pragma unroll
            for (int i = 0; i < NBI; i++) {
                int rg = w * NBI + i;
                int r = rg * 16 + rowInC;
                if (!NMASK || r < Nrem)
                    gld16(Bb + (size_t)r * ldb + (k0 + 32) + cSw * 8,
                          Bs + nb * BBUF + rg * 512);
            }
        }
        const ushort* Ax = As + buf * 4096;
        const ushort* Bx = Bs + buf * BBUF;
        short8 af[4], bf[NF];
#pragma unroll
        for (int i = 0; i < 4; i++)
            af[i] = *(const short8*)&Ax[(wm + i * 16 + l15) * 32 + ((quad ^ sw8)) * 8];
#pragma unroll
        for (int j = 0; j < NF; j++)
            bf[j] = *(const short8*)&Bx[(wn + j * 16 + l15) * 32 + ((quad ^ sw8)) * 8];
#pragma unroll
        for (int i = 0; i < 4; i++)
#pragma unroll
            for (int j = 0; j < NF; j++)
                acc[i][j] = __builtin_amdgcn_mfma_f32_16x16x32_bf16(af[i], bf[j], acc[i][j], 0, 0, 0);
        buf = nb;
    }
}

// ---------- GEMM2 split-K=2: 128m x 192n tiles, fp16 partials ----------
__global__ __launch_bounds__(256) void gemm2_split(const ushort* __restrict__ A,
                                                   const ushort* __restrict__ Bt,
                                                   __half* __restrict__ agg0,
                                                   __half* __restrict__ agg1) {
    __shared__ ushort As[2 * 4096];
    __shared__ ushort Bs[2 * 6144];
    int i0 = blockIdx.x;
    int z = i0 & 7;
    int b = z >> 1, split = z & 1;
    int tile = i0 >> 3;                      // 0..53
    int ty = tile / 3, tx = tile - ty * 3;   // 18 m-tiles x 3 n-tiles
    int m0 = ty * 128, n0 = tx * 192;
    const ushort* Ab = A + (size_t)b * HWp * KPAD + (size_t)m0 * KPAD;
    const ushort* Bb = Bt + (size_t)b * KK * KPAD + (size_t)n0 * KPAD;
    float4v acc[4][6];
#pragma unroll
    for (int i = 0; i < 4; i++)
#pragma unroll
        for (int j = 0; j < 6; j++) acc[i][j] = (float4v){0.f, 0.f, 0.f, 0.f};

    gemm_tile_db<6, false>(Ab, Bb, KPAD, KPAD, split ? KSPLIT0 : 0,
                           split ? KPAD : KSPLIT0, 192, As, Bs, acc);

    int tid = threadIdx.x;
    int lane = tid & 63, wid = tid >> 6;
    int quad = lane >> 4, l15 = lane & 15;
    int wm = (wid >> 1) * 64, wn = (wid & 1) * 96;
    __half* C = (split ? agg1 : agg0) + (size_t)b * HWp * KK;
#pragma unroll
    for (int i = 0; i < 4; i++) {
#pragma unroll
        for (int j = 0; j < 6; j++) {
            int n = n0 + wn + j * 16 + l15;
#pragma unroll
            for (int r = 0; r < 4; r++) {
                int m = m0 + wm + i * 16 + quad * 4 + r;
                C[(size_t)m * KK + n] = __float2half(acc[i][j][r]);
            }
        }
    }
}

// ---------- final: sum 2 split partials, 9-shift combine, ACL, concat, W2, ELU ----------
__global__ __launch_bounds__(256) void final_k(const float* __restrict__ g,
                                               const float* __restrict__ mask,
                                               const __half* __restrict__ agg0,
                                               const __half* __restrict__ agg1,
                                               const float* __restrict__ W2,
                                               const float* __restrict__ b2,
                                               float* __restrict__ out) {
    int w = threadIdx.x >> 6, d = threadIdx.x & 63;
    int pix = blockIdx.x * 4 + w;
    int b = pix / HWp, yx = pix % HWp;
    int y = yx / WW, x = yx % WW;

    __shared__ float con1[4][128];
    float acl = 0.f;
#pragma unroll
    for (int dy = 0; dy < 3; dy++) {
#pragma unroll
        for (int dx = 0; dx < 3; dx++) {
            int yy = y + 1 - dy, xx = x + 1 - dx;
            if (yy >= 0 && yy < HH && xx >= 0 && xx < WW) {
                size_t off = ((size_t)(b * HWp + yy * WW + xx)) * KK + (dy * 3 + dx) * DD + d;
                acl += __half2float(agg0[off]) + __half2float(agg1[off]);
            }
        }
    }
    float m = mask[pix];
    float gv = g[(size_t)pix * DD + d];
    float bgv = gv * m;
    float ACL = bgv + (acl / 9.f) * (1.f - m);
    con1[w][d] = gv;
    con1[w][64 + d] = ACL;
    __syncthreads();
    float accv = b2[d];
#pragma unroll 8
    for (int k = 0; k < 128; k++) accv = fmaf(con1[w][k], W2[k * 64 + d], accv);
    out[(size_t)pix * DD + d] = accv > 0.f ? accv : expm1f(accv);
}

extern "C" void kernel_launch(void* const* d_in, const int* in_sizes, int n_in,
                              void* d_out, int out_size, void* d_ws, size_t ws_size,
                              hipStream_t stream) {
    const float* g    = (const float*)d_in[0];
    const float* mask = (const float*)d_in[1];
    const float* W2   = (const float*)d_in[2];
    const float* b2   = (const float*)d_in[3];
    float* out = (float*)d_out;
    char* ws = (char*)d_ws;

    ushort* gpad  = (ushort*)(ws + OFFB_GPAD);
    ushort* bgpad = (ushort*)(ws + OFFB_BGPAD);
    float*  e     = (float*) (ws + OFFB_E);
    float*  k1d   = (float*) (ws + OFFB_K1D);
    ushort* p1t   = (ushort*)(ws + OFFB_P1T);
    ushort* CA    = (ushort*)(ws + OFFB_S);
    __half* agg0  = (__half*)(ws + OFFB_AGG0);
    __half* agg1  = (__half*)(ws + OFFB_AGG1);
    __half* Qbuf  = (__half*)(ws + OFFB_Q);

    build_pads<<<BB * PP / 4, 256, 0, stream>>>(g, mask, gpad, bgpad, e);
    build_p1t<<<dim3(36, 9, BB), 256, 0, stream>>>(bgpad, e, p1t, k1d);

    qgemm<<<1440, 256, 0, stream>>>(gpad, bgpad, Qbuf);
    qrowsoft<<<BB * HWp, 320, 0, stream>>>(Qbuf, k1d, CA);

    gemm2_split<<<432, 256, 0, stream>>>(CA, p1t, agg0, agg1);

    final_k<<<BB * HWp / 4, 256, 0, stream>>>(g, mask, agg0, agg1, W2, b2, out);
}

// Round 2
// 182.172 us; speedup vs baseline: 1.0565x; 1.0565x over previous
//
#include <hip/hip_runtime.h>
#include <hip/hip_fp16.h>
#include <math.h>

// Problem constants
#define BB 4
#define HH 48
#define WW 48
#define DD 64
#define CH 46
#define CWp 46
#define CC (CH*CWp)      // 2116 (true column count, for softmax stats)
#define KK 576           // 9*64
#define HWp (HH*WW)      // 2304
#define PW 50            // zero-padded field width
#define PP (PW*PW)       // 2500 padded pixels

// slot space: j padded per-row 46->48 -> K width 2208 = 69*32 (dummies are zero)
#define SLOTW 48
#define NSLOT 2208
#define NGRP 276         // 2208/8 groups of 8 slots
#define KPAD NSLOT       // row stride of CA & p1t
#define KSPLIT0 1120     // 35*32; split1 = [1120,2208) = 34 iters
#define QW 2304          // Q row width (v-domain = 48*48)
#define QROWS 2500       // Q rows (u-domain = 50*50)

typedef __attribute__((ext_vector_type(8))) short short8;
typedef __attribute__((ext_vector_type(4))) float float4v;

// ---------- workspace layout (byte offsets, all 16B-aligned) ----------
#define OFFB_GPAD  ((size_t)0)            // bf16 [B][2500][64]    1,280,000 B
#define OFFB_BGPAD ((size_t)1280000)      // bf16 [B][2500][64]    1,280,000 B
#define OFFB_E     ((size_t)2560000)      // f32  [B][2304]           36,864 B
#define OFFB_K1D   ((size_t)2596864)      // f32  [B][2208]           35,328 B
#define OFFB_P1T   ((size_t)2632192)      // bf16 [B][576][2208]  10,174,464 B
#define OFFB_S     ((size_t)12806656)     // bf16 CA [B][HW][2208] 40,697,856 B
#define OFFB_AGG0  ((size_t)53504512)     // fp16 [B][HW][576]    10,616,832 B
#define OFFB_AGG1  ((size_t)64121344)     // fp16 [B][HW][576]    10,616,832 B
#define OFFB_Q     ((size_t)74738176)     // fp16 [B][2500][2304] 46,080,000 B
// total 120,818,176 B (fill evidence: ws allocation is 256 MiB)

// ---------- helpers ----------
__device__ __forceinline__ ushort f2bf(float x) {
    unsigned u = __float_as_uint(x);
    return (ushort)((u + 0x7FFFu + ((u >> 16) & 1u)) >> 16);
}

__device__ __forceinline__ float waveReduceSum(float x) {
#pragma unroll
    for (int o = 32; o > 0; o >>= 1) x += __shfl_down(x, o, 64);
    return x;
}

__device__ __forceinline__ __half2 u2h2(uint u) {
    union { uint u; __half2 h; } c; c.u = u; return c.h;
}

// packed f32x2 -> bf16x2 (RNE), one instruction
__device__ __forceinline__ uint cvtpk_bf16(float lo, float hi) {
    uint r;
    asm("v_cvt_pk_bf16_f32 %0, %1, %2" : "=v"(r) : "v"(lo), "v"(hi));
    return r;
}

// exp(-50*tanh(z)) with tanh folded: = exp(-50 + 100/(e^{2z}+1))
__device__ __forceinline__ float softexp(float d, float mu, float isd) {
    float z = (d - mu) * isd;
    float E2 = __expf(z + z);
    float r = __builtin_amdgcn_rcpf(E2 + 1.f);
    return __expf(fmaf(100.f, r, -50.f));
}

// async 16B global->LDS (wave-uniform LDS base + lane*16)
typedef __attribute__((address_space(3))) void lds_void_t;
typedef __attribute__((address_space(1))) void gmem_void_t;
__device__ __forceinline__ void gld16(const ushort* g, ushort* lds) {
    __builtin_amdgcn_global_load_lds((gmem_void_t*)g, (lds_void_t*)lds, 16, 0, 0);
}

// ---------- build padded fields: gpad = bf16(g), bgpad = bf16(g*mask), e = sum_c bg^2 ----------
__global__ __launch_bounds__(256) void build_pads(const float* __restrict__ g,
                                                  const float* __restrict__ mask,
                                                  ushort* __restrict__ gpad,
                                                  ushort* __restrict__ bgpad,
                                                  float* __restrict__ e) {
    int w = threadIdx.x >> 6, c = threadIdx.x & 63;
    int q4 = blockIdx.x * 4 + w;         // [0, B*2500)
    int b = q4 / PP, q = q4 % PP;
    int yp = q / PW, xp = q % PW;
    size_t o = (size_t)q4 * DD + c;
    if (yp >= 1 && yp <= HH && xp >= 1 && xp <= WW) {
        int pix = (yp - 1) * WW + (xp - 1);
        float gv = g[((size_t)b * HWp + pix) * DD + c];
        float m  = mask[(size_t)b * HWp + pix];
        float bgv = gv * m;
        gpad[o]  = f2bf(gv);
        bgpad[o] = f2bf(bgv);
        float ss = waveReduceSum(bgv * bgv);
        if (c == 0) e[b * HWp + pix] = ss;
    } else {
        gpad[o] = 0;
        bgpad[o] = 0;
    }
}

// ---------- p1t via LDS-tiled transpose from bgpad (slot space, + k1d) ----------
__global__ __launch_bounds__(256) void build_p1t(const ushort* __restrict__ bgpad,
                                                 const float* __restrict__ e,
                                                 ushort* __restrict__ p1t,
                                                 float* __restrict__ k1d) {
    int d9 = blockIdx.y, b = blockIdx.z;
    int t = threadIdx.x;
    if (blockIdx.x == 35) {
        int jg = (b * 9 + d9) * 256 + t;         // [0, 9216)
        if (jg < BB * NSLOT) {
            int bb = jg / NSLOT, st = jg - bb * NSLOT;
            int jy = st / SLOTW, jx = st - jy * SLOTW;   // jy <= 45 here
            float s = 0.f;
            if (jx < CWp) {
                const float* eb = e + bb * HWp + jy * WW + jx;
#pragma unroll
                for (int ddy = 0; ddy < 3; ddy++)
#pragma unroll
                    for (int ddx = 0; ddx < 3; ddx++) s += eb[ddy * WW + ddx];
            }
            k1d[jg] = s;
        }
        return;
    }
    __shared__ ushort T[64 * 65];
    int jt = blockIdx.x;                 // 0..34 (35*64 = 2240 >= 2208)
    int dy = d9 / 3, dx = d9 - dy * 3;
    const ushort* src = bgpad + (size_t)b * PP * DD;
    int lr = t >> 3, c8 = (t & 7) * 8;
#pragma unroll
    for (int pass = 0; pass < 2; pass++) {
        int r = lr + pass * 32;
        int st = jt * 64 + r;
        int jy = st / SLOTW, jx = st - jy * SLOTW;
        uint4 d = make_uint4(0, 0, 0, 0);
        if (jx < CWp && jy < CWp)
            d = *(const uint4*)(src + (size_t)((jy + dy + 1) * PW + (jx + dx + 1)) * DD + c8);
        ushort tmp[8];
        *(uint4*)tmp = d;
#pragma unroll
        for (int u = 0; u < 8; u++) T[r * 65 + c8 + u] = tmp[u];
    }
    __syncthreads();
#pragma unroll
    for (int pass = 0; pass < 2; pass++) {
        int c = lr + pass * 32;
        int j8 = (t & 7) * 8;
        int col0 = jt * 64 + j8;
        ushort tmp[8];
#pragma unroll
        for (int u = 0; u < 8; u++) tmp[u] = T[(j8 + u) * 65 + c];
        if (col0 < NSLOT)
            *(uint4*)(p1t + ((size_t)b * KK + d9 * 64 + c) * NSLOT + col0) = *(const uint4*)tmp;
    }
}

// ---------- Q-gemm: Q[u,v] = sum_d gpad[u,d]*bg[v,d], K=64, fp16 out ----------
__global__ __launch_bounds__(256) void qgemm(const ushort* __restrict__ gpad,
                                             const ushort* __restrict__ bgpad,
                                             __half* __restrict__ Qout) {
    __shared__ ushort As[2 * 4096];
    __shared__ ushort Bs[2 * 4096];
    int i0 = blockIdx.x;
    int b = (i0 & 7) >> 1;                    // batch pinned to XCD pair
    int tile = ((i0 >> 3) << 1) | (i0 & 1);   // 0..359, bijective
    int ty = tile / 18, tx = tile - ty * 18;
    int m0 = ty * 128, n0 = tx * 128;
    const ushort* Ag = gpad + (size_t)b * PP * DD;
    const ushort* Bg = bgpad + (size_t)b * PP * DD;

    int tid = threadIdx.x;
    int l = tid & 63, w = tid >> 6;
    int quad = l >> 4, l15 = l & 15;
    int sw8 = (l15 >> 1) & 3;
    int wm = (w >> 1) * 64, wn = (w & 1) * 64;
    int rowInC = l >> 2;
    int cSw = (l & 3) ^ ((l >> 3) & 3);

    // stage both K-halves up front (K=64 total)
#pragma unroll
    for (int i = 0; i < 2; i++) {
        int rg = w * 2 + i;
        int r = rg * 16 + rowInC;
        int u = m0 + r; if (u > QROWS - 1) u = QROWS - 1;  // clamp; store-guarded
        int n = n0 + r;                                     // < 2304 always
        int vy = n / 48, vx = n - vy * 48;
        int baseA = u * DD + cSw * 8;
        int baseB = ((vy + 1) * PW + (vx + 1)) * DD + cSw * 8;
        gld16(Ag + baseA, As + rg * 512);
        gld16(Bg + baseB, Bs + rg * 512);
        gld16(Ag + baseA + 32, As + 4096 + rg * 512);
        gld16(Bg + baseB + 32, Bs + 4096 + rg * 512);
    }
    float4v acc[4][4];
#pragma unroll
    for (int i = 0; i < 4; i++)
#pragma unroll
        for (int j = 0; j < 4; j++) acc[i][j] = (float4v){0.f, 0.f, 0.f, 0.f};
    __syncthreads();
#pragma unroll
    for (int kb = 0; kb < 2; kb++) {
        const ushort* Ax = As + kb * 4096;
        const ushort* Bx = Bs + kb * 4096;
        short8 af[4], bf[4];
#pragma unroll
        for (int i = 0; i < 4; i++)
            af[i] = *(const short8*)&Ax[(wm + i * 16 + l15) * 32 + ((quad ^ sw8)) * 8];
#pragma unroll
        for (int j = 0; j < 4; j++)
            bf[j] = *(const short8*)&Bx[(wn + j * 16 + l15) * 32 + ((quad ^ sw8)) * 8];
#pragma unroll
        for (int i = 0; i < 4; i++)
#pragma unroll
            for (int j = 0; j < 4; j++)
                acc[i][j] = __builtin_amdgcn_mfma_f32_16x16x32_bf16(af[i], bf[j], acc[i][j], 0, 0, 0);
    }
    __half* C = Qout + (size_t)b * QROWS * QW;
#pragma unroll
    for (int i = 0; i < 4; i++) {
#pragma unroll
        for (int j = 0; j < 4; j++) {
            int n = n0 + wn + j * 16 + l15;
#pragma unroll
            for (int r = 0; r < 4; r++) {
                int m = m0 + wm + i * 16 + quad * 4 + r;
                if (m < QROWS) C[(size_t)m * QW + n] = __float2half(acc[i][j][r]);
            }
        }
    }
}

// ---------- fused 9-point box-sum + standardize + -50*tanh + softmax -> bf16 CA ----------
// 8 x-consecutive pixels per block; thread t owns slot-group t (t<276) for all 8 pixels.
// Per band dy: 10 consecutive Q rows, one 20B window each, shared across pixels
// (v-window = slot0 + dy*48 + dx depends only on (dy,dx)). fp16 pk_add accumulation.
__global__ __launch_bounds__(320) void qrowsoft2(const __half* __restrict__ Q,
                                                 const float* __restrict__ k1d,
                                                 ushort* __restrict__ CA) {
    __shared__ float red[16][321];   // transpose-reduce scratch; col 320 = results
    int i0 = blockIdx.x;
    int z = i0 & 7;
    int b = z >> 1;                              // batch pinned to XCD pair
    int sub = ((i0 >> 3) << 1) | (i0 & 1);       // 0..287, bijective
    int y = sub / 6, xt = sub - y * 6;
    int x0 = xt * 8;

    int t = threadIdx.x;
    bool act = (t < NGRP);
    int jy = t / 6, jxb = (t - jy * 6) * 8;      // only meaningful for act
    int slot0 = jy * SLOTW + jxb;
    bool vc6 = act && (jxb == 40);               // last 6-slot group of each jy row

    __half2 acc[8][4];
#pragma unroll
    for (int p = 0; p < 8; p++)
#pragma unroll
        for (int k = 0; k < 4; k++) acc[p][k] = u2h2(0u);

    float k1v[8] = {0.f, 0.f, 0.f, 0.f, 0.f, 0.f, 0.f, 0.f};

    if (act) {
        // k1d slice (zero-filled for pad slots)
        const float* k1 = k1d + (size_t)b * NSLOT + slot0;
        float4 ka = *(const float4*)k1;
        float4 kb = *(const float4*)(k1 + 4);
        k1v[0] = ka.x; k1v[1] = ka.y; k1v[2] = ka.z; k1v[3] = ka.w;
        k1v[4] = kb.x; k1v[5] = kb.y; k1v[6] = kb.z; k1v[7] = kb.w;

#pragma unroll 1
        for (int dy = 0; dy < 3; dy++) {
            const __half* rp = Q + ((size_t)b * QROWS + (size_t)(y + dy) * PW + x0) * QW
                               + slot0 + dy * 48;
            uint4 W4[10]; uint W1[10];
#pragma unroll
            for (int d = 0; d < 10; d++) {
                const __half* pr = rp + (size_t)d * QW;
                W4[d] = *(const uint4*)pr;
                W1[d] = *(const uint*)(pr + 8);
            }
#pragma unroll
            for (int d = 0; d < 10; d++) {
                uint w0 = W4[d].x, w1 = W4[d].y, w2 = W4[d].z, w3 = W4[d].w, w4 = W1[d];
                if (d < 8) {                      // dx=0 -> pixel d
                    acc[d][0] = __hadd2(acc[d][0], u2h2(w0));
                    acc[d][1] = __hadd2(acc[d][1], u2h2(w1));
                    acc[d][2] = __hadd2(acc[d][2], u2h2(w2));
                    acc[d][3] = __hadd2(acc[d][3], u2h2(w3));
                }
                if (d >= 1 && d <= 8) {           // dx=1 -> pixel d-1 (shift by 1 half)
                    uint s0 = (w0 >> 16) | (w1 << 16);
                    uint s1 = (w1 >> 16) | (w2 << 16);
                    uint s2 = (w2 >> 16) | (w3 << 16);
                    uint s3 = (w3 >> 16) | (w4 << 16);
                    acc[d-1][0] = __hadd2(acc[d-1][0], u2h2(s0));
                    acc[d-1][1] = __hadd2(acc[d-1][1], u2h2(s1));
                    acc[d-1][2] = __hadd2(acc[d-1][2], u2h2(s2));
                    acc[d-1][3] = __hadd2(acc[d-1][3], u2h2(s3));
                }
                if (d >= 2) {                     // dx=2 -> pixel d-2 (shift by 1 uint)
                    acc[d-2][0] = __hadd2(acc[d-2][0], u2h2(w1));
                    acc[d-2][1] = __hadd2(acc[d-2][1], u2h2(w2));
                    acc[d-2][2] = __hadd2(acc[d-2][2], u2h2(w3));
                    acc[d-2][3] = __hadd2(acc[d-2][3], u2h2(w4));
                }
            }
        }
    }

    // purge pad-slot garbage (possible cross-row bytes feed only halves 6,7)
    if (vc6) {
#pragma unroll
        for (int p = 0; p < 8; p++) acc[p][3] = u2h2(0u);
    }

    // ---- phase A: per-pixel sum & sumsq of ds = k1 - 2*cs (pad slots contribute 0) ----
#pragma unroll
    for (int p = 0; p < 8; p++) {
        float s1p = 0.f, s2p = 0.f;
#pragma unroll
        for (int k = 0; k < 4; k++) {
            float2 f = __half22float2(acc[p][k]);
            float d0 = k1v[2*k]   - 2.f * f.x;
            float d1 = k1v[2*k+1] - 2.f * f.y;
            s1p += d0 + d1;
            s2p = fmaf(d0, d0, fmaf(d1, d1, s2p));
        }
        red[p][t] = s1p;
        red[8 + p][t] = s2p;
    }
    __syncthreads();
    if (t < 256) {
        int v = t >> 4, sb = t & 15;
        float s = 0.f;
#pragma unroll
        for (int k = 0; k < 20; k++) s += red[v][sb + 16 * k];
#pragma unroll
        for (int o = 8; o > 0; o >>= 1) s += __shfl_down(s, o, 16);
        if (sb == 0) red[v][320] = s;
    }
    __syncthreads();
    float mu[8], isd[8];
#pragma unroll
    for (int p = 0; p < 8; p++) {
        float m = red[p][320] * (1.f / (float)CC);
        float ex2 = red[8 + p][320] * (1.f / (float)CC);
        mu[p] = m;
        isd[p] = rsqrtf(ex2 - m * m);
    }

    // ---- exp pass: pack unnormalized exp as bf16 pairs, accumulate es ----
    uint eb[8][4];
#pragma unroll
    for (int p = 0; p < 8; p++) {
        float es = 0.f;
#pragma unroll
        for (int k = 0; k < 4; k++) {
            float2 f = __half22float2(acc[p][k]);
            float d0 = k1v[2*k]   - 2.f * f.x;
            float d1 = k1v[2*k+1] - 2.f * f.y;
            if (k == 3 && vc6) { d0 = 1e9f; d1 = 1e9f; }   // pad slots -> exp ~ e^-50 ~ 0
            float e0 = softexp(d0, mu[p], isd[p]);
            float e1 = softexp(d1, mu[p], isd[p]);
            es += e0 + e1;
            eb[p][k] = cvtpk_bf16(e0, e1);
        }
        red[p][t] = act ? es : 0.f;
    }
    __syncthreads();
    if (t < 128) {
        int v = t >> 4, sb = t & 15;
        float s = 0.f;
#pragma unroll
        for (int k = 0; k < 20; k++) s += red[v][sb + 16 * k];
#pragma unroll
        for (int o = 8; o > 0; o >>= 1) s += __shfl_down(s, o, 16);
        if (sb == 0) red[v][320] = s;
    }
    __syncthreads();

    // ---- normalize (unpack bf16, *invz, repack) and store ----
    if (act) {
#pragma unroll
        for (int p = 0; p < 8; p++) {
            float iz = __builtin_amdgcn_rcpf(red[p][320]);
            uint o[4];
#pragma unroll
            for (int k = 0; k < 4; k++) {
                uint w = eb[p][k];
                float lo = __uint_as_float(w << 16) * iz;
                float hi = __uint_as_float(w & 0xffff0000u) * iz;
                o[k] = cvtpk_bf16(lo, hi);
            }
            int pix = y * WW + x0 + p;
            ushort* wp = CA + ((size_t)b * HWp + pix) * (size_t)NSLOT + slot0;
            *(uint4*)wp = *(const uint4*)o;
        }
    }
}

// ---------- MFMA GEMM core (NT), BK=32, double-buffered (for GEMM2) ----------
template <int NF, bool NMASK>
__device__ __forceinline__ void gemm_tile_db(const ushort* __restrict__ Ab,
                                             const ushort* __restrict__ Bb,
                                             int lda, int ldb, int kb, int ke,
                                             int Nrem,
                                             ushort* As, ushort* Bs,
                                             float4v (&acc)[4][NF]) {
    constexpr int NBI = NF / 2;
    constexpr int BBUF = 2048 * NBI;          // ushorts per B buffer
    int tid = threadIdx.x;
    int l = tid & 63, w = tid >> 6;
    int quad = l >> 4, l15 = l & 15;
    int sw8 = (l15 >> 1) & 3;
    int wm = (w >> 1) * 64, wn = (w & 1) * (NF * 16);
    int rowInC = l >> 2;
    int cSw = (l & 3) ^ ((l >> 3) & 3);

#pragma unroll
    for (int i = 0; i < 2; i++) {
        int rg = w * 2 + i;
        gld16(Ab + (size_t)(rg * 16 + rowInC) * lda + kb + cSw * 8, As + rg * 512);
    }
#pragma unroll
    for (int i = 0; i < NBI; i++) {
        int rg = w * NBI + i;
        int r = rg * 16 + rowInC;
        if (!NMASK || r < Nrem)
            gld16(Bb + (size_t)r * ldb + kb + cSw * 8, Bs + rg * 512);
    }

    int buf = 0;
    for (int k0 = kb; k0 < ke; k0 += 32) {
        __syncthreads();
        int nb = buf ^ 1;
        if (k0 + 32 < ke) {
#pragma unroll
            for (int i = 0; i < 2; i++) {
                int rg = w * 2 + i;
                gld16(Ab + (size_t)(rg * 16 + rowInC) * lda + (k0 + 32) + cSw * 8,
                      As + nb * 4096 + rg * 512);
            }
#pragma unroll
            for (int i = 0; i < NBI; i++) {
                int rg = w * NBI + i;
                int r = rg * 16 + rowInC;
                if (!NMASK || r < Nrem)
                    gld16(Bb + (size_t)r * ldb + (k0 + 32) + cSw * 8,
                          Bs + nb * BBUF + rg * 512);
            }
        }
        const ushort* Ax = As + buf * 4096;
        const ushort* Bx = Bs + buf * BBUF;
        short8 af[4], bf[NF];
#pragma unroll
        for (int i = 0; i < 4; i++)
            af[i] = *(const short8*)&Ax[(wm + i * 16 + l15) * 32 + ((quad ^ sw8)) * 8];
#pragma unroll
        for (int j = 0; j < NF; j++)
            bf[j] = *(const short8*)&Bx[(wn + j * 16 + l15) * 32 + ((quad ^ sw8)) * 8];
#pragma unroll
        for (int i = 0; i < 4; i++)
#pragma unroll
            for (int j = 0; j < NF; j++)
                acc[i][j] = __builtin_amdgcn_mfma_f32_16x16x32_bf16(af[i], bf[j], acc[i][j], 0, 0, 0);
        buf = nb;
    }
}

// ---------- GEMM2 split-K=2: 128m x 192n tiles, fp16 partials ----------
__global__ __launch_bounds__(256) void gemm2_split(const ushort* __restrict__ A,
                                                   const ushort* __restrict__ Bt,
                                                   __half* __restrict__ agg0,
                                                   __half* __restrict__ agg1) {
    __shared__ ushort As[2 * 4096];
    __shared__ ushort Bs[2 * 6144];
    int i0 = blockIdx.x;
    int z = i0 & 7;
    int b = z >> 1, split = z & 1;
    int tile = i0 >> 3;                      // 0..53
    int ty = tile / 3, tx = tile - ty * 3;   // 18 m-tiles x 3 n-tiles
    int m0 = ty * 128, n0 = tx * 192;
    const ushort* Ab = A + (size_t)b * HWp * KPAD + (size_t)m0 * KPAD;
    const ushort* Bb = Bt + (size_t)b * KK * KPAD + (size_t)n0 * KPAD;
    float4v acc[4][6];
#pragma unroll
    for (int i = 0; i < 4; i++)
#pragma unroll
        for (int j = 0; j < 6; j++) acc[i][j] = (float4v){0.f, 0.f, 0.f, 0.f};

    gemm_tile_db<6, false>(Ab, Bb, KPAD, KPAD, split ? KSPLIT0 : 0,
                           split ? KPAD : KSPLIT0, 192, As, Bs, acc);

    int tid = threadIdx.x;
    int lane = tid & 63, wid = tid >> 6;
    int quad = lane >> 4, l15 = lane & 15;
    int wm = (wid >> 1) * 64, wn = (wid & 1) * 96;
    __half* C = (split ? agg1 : agg0) + (size_t)b * HWp * KK;
#pragma unroll
    for (int i = 0; i < 4; i++) {
#pragma unroll
        for (int j = 0; j < 6; j++) {
            int n = n0 + wn + j * 16 + l15;
#pragma unroll
            for (int r = 0; r < 4; r++) {
                int m = m0 + wm + i * 16 + quad * 4 + r;
                C[(size_t)m * KK + n] = __float2half(acc[i][j][r]);
            }
        }
    }
}

// ---------- final: sum 2 split partials, 9-shift combine, ACL, concat, W2, ELU ----------
__global__ __launch_bounds__(256) void final_k(const float* __restrict__ g,
                                               const float* __restrict__ mask,
                                               const __half* __restrict__ agg0,
                                               const __half* __restrict__ agg1,
                                               const float* __restrict__ W2,
                                               const float* __restrict__ b2,
                                               float* __restrict__ out) {
    int w = threadIdx.x >> 6, d = threadIdx.x & 63;
    int pix = blockIdx.x * 4 + w;
    int b = pix / HWp, yx = pix % HWp;
    int y = yx / WW, x = yx % WW;

    __shared__ float con1[4][128];
    float acl = 0.f;
#pragma unroll
    for (int dy = 0; dy < 3; dy++) {
#pragma unroll
        for (int dx = 0; dx < 3; dx++) {
            int yy = y + 1 - dy, xx = x + 1 - dx;
            if (yy >= 0 && yy < HH && xx >= 0 && xx < WW) {
                size_t off = ((size_t)(b * HWp + yy * WW + xx)) * KK + (dy * 3 + dx) * DD + d;
                acl += __half2float(agg0[off]) + __half2float(agg1[off]);
            }
        }
    }
    float m = mask[pix];
    float gv = g[(size_t)pix * DD + d];
    float bgv = gv * m;
    float ACL = bgv + (acl / 9.f) * (1.f - m);
    con1[w][d] = gv;
    con1[w][64 + d] = ACL;
    __syncthreads();
    float accv = b2[d];
#pragma unroll 8
    for (int k = 0; k < 128; k++) accv = fmaf(con1[w][k], W2[k * 64 + d], accv);
    out[(size_t)pix * DD + d] = accv > 0.f ? accv : expm1f(accv);
}

extern "C" void kernel_launch(void* const* d_in, const int* in_sizes, int n_in,
                              void* d_out, int out_size, void* d_ws, size_t ws_size,
                              hipStream_t stream) {
    const float* g    = (const float*)d_in[0];
    const float* mask = (const float*)d_in[1];
    const float* W2   = (const float*)d_in[2];
    const float* b2   = (const float*)d_in[3];
    float* out = (float*)d_out;
    char* ws = (char*)d_ws;

    ushort* gpad  = (ushort*)(ws + OFFB_GPAD);
    ushort* bgpad = (ushort*)(ws + OFFB_BGPAD);
    float*  e     = (float*) (ws + OFFB_E);
    float*  k1d   = (float*) (ws + OFFB_K1D);
    ushort* p1t   = (ushort*)(ws + OFFB_P1T);
    ushort* CA    = (ushort*)(ws + OFFB_S);
    __half* agg0  = (__half*)(ws + OFFB_AGG0);
    __half* agg1  = (__half*)(ws + OFFB_AGG1);
    __half* Qbuf  = (__half*)(ws + OFFB_Q);

    build_pads<<<BB * PP / 4, 256, 0, stream>>>(g, mask, gpad, bgpad, e);
    build_p1t<<<dim3(36, 9, BB), 256, 0, stream>>>(bgpad, e, p1t, k1d);

    qgemm<<<1440, 256, 0, stream>>>(gpad, bgpad, Qbuf);
    qrowsoft2<<<BB * HWp / 8, 320, 0, stream>>>(Qbuf, k1d, CA);

    gemm2_split<<<432, 256, 0, stream>>>(CA, p1t, agg0, agg1);

    final_k<<<BB * HWp / 4, 256, 0, stream>>>(g, mask, agg0, agg1, W2, b2, out);
}

// Round 3
// 167.715 us; speedup vs baseline: 1.1475x; 1.0862x over previous
//
#include <hip/hip_runtime.h>
#include <hip/hip_fp16.h>
#include <math.h>

// Problem constants
#define BB 4
#define HH 48
#define WW 48
#define DD 64
#define CH 46
#define CWp 46
#define CC (CH*CWp)      // 2116 (true column count, for softmax stats)
#define KK 576           // 9*64
#define HWp (HH*WW)      // 2304
#define PW 50            // zero-padded field width
#define PP (PW*PW)       // 2500 padded pixels

// slot space: j padded per-row 46->48 -> K width 2208 (dummies are zero)
#define SLOTW 48
#define NSLOT 2208
#define NGRP 276         // 2208/8 groups of 8 slots
#define QW 2304          // Q row width (v-domain = 48*48); also W col width
#define QROWS 2500       // Q rows (u-domain = 50*50)

typedef __attribute__((ext_vector_type(8))) short short8;
typedef __attribute__((ext_vector_type(8))) _Float16 half8;
typedef __attribute__((ext_vector_type(4))) float float4v;

// ---------- workspace layout (byte offsets, all 16B-aligned) ----------
#define OFFB_GPAD  ((size_t)0)            // bf16 [B][2500][64]     1,280,000 B
#define OFFB_BGPAD ((size_t)1280000)      // bf16 [B][2500][64]     1,280,000 B
#define OFFB_E     ((size_t)2560000)      // f32  [B][2304]            36,864 B
#define OFFB_K1D   ((size_t)2596864)      // f32  [B][2208]            35,328 B
#define OFFB_BGT   ((size_t)2632192)      // fp16 [B][64][2304]     1,179,648 B
#define OFFB_Q     ((size_t)3811840)      // fp16 [B][2500][2304]  46,080,000 B
#define OFFB_S     ((size_t)49891840)     // fp16 CA [B][2304][2208] 40,697,856 B
#define OFFB_W     ((size_t)90589696)     // fp16 W  [B][2304][2304] 42,467,328 B
#define OFFB_ACL   ((size_t)133057024)    // f32  [8][B*2304][64]  18,874,368 B
// total 151,931,392 B (fill evidence: ws allocation is 256 MiB)

// ---------- helpers ----------
__device__ __forceinline__ ushort f2bf(float x) {
    unsigned u = __float_as_uint(x);
    return (ushort)((u + 0x7FFFu + ((u >> 16) & 1u)) >> 16);
}

__device__ __forceinline__ float waveReduceSum(float x) {
#pragma unroll
    for (int o = 32; o > 0; o >>= 1) x += __shfl_down(x, o, 64);
    return x;
}

__device__ __forceinline__ __half2 u2h2(uint u) {
    union { uint u; __half2 h; } c; c.u = u; return c.h;
}

// packed f32x2 -> bf16x2 (RNE), one instruction
__device__ __forceinline__ uint cvtpk_bf16(float lo, float hi) {
    uint r;
    asm("v_cvt_pk_bf16_f32 %0, %1, %2" : "=v"(r) : "v"(lo), "v"(hi));
    return r;
}

// exp(-50*tanh(z)) with tanh folded: = exp(-50 + 100/(e^{2z}+1))
__device__ __forceinline__ float softexp(float d, float mu, float isd) {
    float z = (d - mu) * isd;
    float E2 = __expf(z + z);
    float r = __builtin_amdgcn_rcpf(E2 + 1.f);
    return __expf(fmaf(100.f, r, -50.f));
}

// async 16B global->LDS (wave-uniform LDS base + lane*16)
typedef __attribute__((address_space(3))) void lds_void_t;
typedef __attribute__((address_space(1))) void gmem_void_t;
__device__ __forceinline__ void gld16(const ushort* g, ushort* lds) {
    __builtin_amdgcn_global_load_lds((gmem_void_t*)g, (lds_void_t*)lds, 16, 0, 0);
}

// ---------- build padded fields: gpad = bf16(g), bgpad = bf16(g*mask), e = sum_c bg^2 ----------
__global__ __launch_bounds__(256) void build_pads(const float* __restrict__ g,
                                                  const float* __restrict__ mask,
                                                  ushort* __restrict__ gpad,
                                                  ushort* __restrict__ bgpad,
                                                  float* __restrict__ e) {
    int w = threadIdx.x >> 6, c = threadIdx.x & 63;
    int q4 = blockIdx.x * 4 + w;         // [0, B*2500)
    int b = q4 / PP, q = q4 % PP;
    int yp = q / PW, xp = q % PW;
    size_t o = (size_t)q4 * DD + c;
    if (yp >= 1 && yp <= HH && xp >= 1 && xp <= WW) {
        int pix = (yp - 1) * WW + (xp - 1);
        float gv = g[((size_t)b * HWp + pix) * DD + c];
        float m  = mask[(size_t)b * HWp + pix];
        float bgv = gv * m;
        gpad[o]  = f2bf(gv);
        bgpad[o] = f2bf(bgv);
        float ss = waveReduceSum(bgv * bgv);
        if (c == 0) e[b * HWp + pix] = ss;
    } else {
        gpad[o] = 0;
        bgpad[o] = 0;
    }
}

// ---------- bgT transpose (fp16 [B][64][2304]) + k1d ----------
__global__ __launch_bounds__(256) void build_bgt_k1d(const ushort* __restrict__ bgpad,
                                                     const float* __restrict__ e,
                                                     ushort* __restrict__ bgT,
                                                     float* __restrict__ k1d) {
    int b = blockIdx.y;
    int t = threadIdx.x;
    if (blockIdx.x == 36) {
        // k1d[b][st]: 3x3 window sum of e at slot st=(jy,jx); zero for pad jx
#pragma unroll 1
        for (int st = t; st < NSLOT; st += 256) {
            int jy = st / SLOTW, jx = st - jy * SLOTW;
            float s = 0.f;
            if (jx < CWp) {
                const float* eb = e + (size_t)b * HWp + jy * WW + jx;
#pragma unroll
                for (int ddy = 0; ddy < 3; ddy++)
#pragma unroll
                    for (int ddx = 0; ddx < 3; ddx++) s += eb[ddy * WW + ddx];
            }
            k1d[(size_t)b * NSLOT + st] = s;
        }
        return;
    }
    __shared__ ushort T[64 * 65];
    int jt = blockIdx.x;                 // 0..35, v in [64jt, 64jt+64)
    const ushort* src = bgpad + (size_t)b * PP * DD;
    int lr = t >> 3, c8 = (t & 7) * 8;
#pragma unroll
    for (int pass = 0; pass < 2; pass++) {
        int r = lr + pass * 32;
        int v = jt * 64 + r;
        int vy = v / 48, vx = v - vy * 48;
        uint4 d = *(const uint4*)(src + (size_t)((vy + 1) * PW + (vx + 1)) * DD + c8);
        ushort tmp[8];
        *(uint4*)tmp = d;
#pragma unroll
        for (int u = 0; u < 8; u++) {
            float f = __uint_as_float((uint)tmp[u] << 16);   // bf16 -> f32
            __half h = __float2half_rn(f);
            T[r * 65 + c8 + u] = *(ushort*)&h;
        }
    }
    __syncthreads();
#pragma unroll
    for (int pass = 0; pass < 2; pass++) {
        int c = lr + pass * 32;          // d index
        int j8 = (t & 7) * 8;
        ushort tmp[8];
#pragma unroll
        for (int u = 0; u < 8; u++) tmp[u] = T[(j8 + u) * 65 + c];
        *(uint4*)(bgT + ((size_t)b * 64 + c) * QW + jt * 64 + j8) = *(const uint4*)tmp;
    }
}

// ---------- Q-gemm: Q[u,v] = sum_d gpad[u,d]*bg[v,d], K=64, fp16 out ----------
__global__ __launch_bounds__(256) void qgemm(const ushort* __restrict__ gpad,
                                             const ushort* __restrict__ bgpad,
                                             __half* __restrict__ Qout) {
    __shared__ ushort As[2 * 4096];
    __shared__ ushort Bs[2 * 4096];
    int i0 = blockIdx.x;
    int b = (i0 & 7) >> 1;                    // batch pinned to XCD pair
    int tile = ((i0 >> 3) << 1) | (i0 & 1);   // 0..359, bijective
    int ty = tile / 18, tx = tile - ty * 18;
    int m0 = ty * 128, n0 = tx * 128;
    const ushort* Ag = gpad + (size_t)b * PP * DD;
    const ushort* Bg = bgpad + (size_t)b * PP * DD;

    int tid = threadIdx.x;
    int l = tid & 63, w = tid >> 6;
    int quad = l >> 4, l15 = l & 15;
    int sw8 = (l15 >> 1) & 3;
    int wm = (w >> 1) * 64, wn = (w & 1) * 64;
    int rowInC = l >> 2;
    int cSw = (l & 3) ^ ((l >> 3) & 3);

    // stage both K-halves up front (K=64 total)
#pragma unroll
    for (int i = 0; i < 2; i++) {
        int rg = w * 2 + i;
        int r = rg * 16 + rowInC;
        int u = m0 + r; if (u > QROWS - 1) u = QROWS - 1;  // clamp; store-guarded
        int n = n0 + r;                                     // < 2304 always
        int vy = n / 48, vx = n - vy * 48;
        int baseA = u * DD + cSw * 8;
        int baseB = ((vy + 1) * PW + (vx + 1)) * DD + cSw * 8;
        gld16(Ag + baseA, As + rg * 512);
        gld16(Bg + baseB, Bs + rg * 512);
        gld16(Ag + baseA + 32, As + 4096 + rg * 512);
        gld16(Bg + baseB + 32, Bs + 4096 + rg * 512);
    }
    float4v acc[4][4];
#pragma unroll
    for (int i = 0; i < 4; i++)
#pragma unroll
        for (int j = 0; j < 4; j++) acc[i][j] = (float4v){0.f, 0.f, 0.f, 0.f};
    __syncthreads();
#pragma unroll
    for (int kb = 0; kb < 2; kb++) {
        const ushort* Ax = As + kb * 4096;
        const ushort* Bx = Bs + kb * 4096;
        short8 af[4], bf[4];
#pragma unroll
        for (int i = 0; i < 4; i++)
            af[i] = *(const short8*)&Ax[(wm + i * 16 + l15) * 32 + ((quad ^ sw8)) * 8];
#pragma unroll
        for (int j = 0; j < 4; j++)
            bf[j] = *(const short8*)&Bx[(wn + j * 16 + l15) * 32 + ((quad ^ sw8)) * 8];
#pragma unroll
        for (int i = 0; i < 4; i++)
#pragma unroll
            for (int j = 0; j < 4; j++)
                acc[i][j] = __builtin_amdgcn_mfma_f32_16x16x32_bf16(af[i], bf[j], acc[i][j], 0, 0, 0);
    }
    __half* C = Qout + (size_t)b * QROWS * QW;
#pragma unroll
    for (int i = 0; i < 4; i++) {
#pragma unroll
        for (int j = 0; j < 4; j++) {
            int n = n0 + wn + j * 16 + l15;
#pragma unroll
            for (int r = 0; r < 4; r++) {
                int m = m0 + wm + i * 16 + quad * 4 + r;
                if (m < QROWS) C[(size_t)m * QW + n] = __float2half(acc[i][j][r]);
            }
        }
    }
}

// ---------- fused 9-point box-sum + standardize + -50*tanh + softmax -> fp16 CA ----------
// 4 x-consecutive pixels per block (2304 blocks -> 11.2 waves/SIMD for latency hiding);
// thread t owns slot-group t (t<276) for all 4 pixels. fp16 pk_add accumulation.
__global__ __launch_bounds__(320) void qrowsoft3(const __half* __restrict__ Q,
                                                 const float* __restrict__ k1d,
                                                 ushort* __restrict__ CA) {
    __shared__ float red[8][321];    // transpose-reduce scratch; col 320 = results
    int i0 = blockIdx.x;
    int b = (i0 & 7) >> 1;                       // batch pinned to XCD pair
    int sub = ((i0 >> 3) << 1) | (i0 & 1);       // 0..575
    int y = sub / 12, xt = sub - y * 12;
    int x0 = xt * 4;

    int t = threadIdx.x;
    bool act = (t < NGRP);
    int jy = t / 6, jxb = (t - jy * 6) * 8;
    int slot0 = jy * SLOTW + jxb;
    bool vc6 = act && (jxb == 40);               // group containing pad slots 46,47

    __half2 acc[4][4];
#pragma unroll
    for (int p = 0; p < 4; p++)
#pragma unroll
        for (int k = 0; k < 4; k++) acc[p][k] = u2h2(0u);

    float k1v[8] = {0.f, 0.f, 0.f, 0.f, 0.f, 0.f, 0.f, 0.f};

    if (act) {
        const float* k1 = k1d + (size_t)b * NSLOT + slot0;
        float4 ka = *(const float4*)k1;
        float4 kb = *(const float4*)(k1 + 4);
        k1v[0] = ka.x; k1v[1] = ka.y; k1v[2] = ka.z; k1v[3] = ka.w;
        k1v[4] = kb.x; k1v[5] = kb.y; k1v[6] = kb.z; k1v[7] = kb.w;

#pragma unroll 1
        for (int dy = 0; dy < 3; dy++) {
            const __half* rp = Q + ((size_t)b * QROWS + (size_t)(y + dy) * PW + x0) * QW
                               + slot0 + dy * 48;
            uint4 W4[6]; uint W1[6];
#pragma unroll
            for (int d = 0; d < 6; d++) {
                const __half* pr = rp + (size_t)d * QW;
                W4[d] = *(const uint4*)pr;
                W1[d] = *(const uint*)(pr + 8);
            }
#pragma unroll
            for (int d = 0; d < 6; d++) {
                uint w0 = W4[d].x, w1 = W4[d].y, w2 = W4[d].z, w3 = W4[d].w, w4 = W1[d];
                if (d < 4) {                      // dx=0 -> pixel d
                    acc[d][0] = __hadd2(acc[d][0], u2h2(w0));
                    acc[d][1] = __hadd2(acc[d][1], u2h2(w1));
                    acc[d][2] = __hadd2(acc[d][2], u2h2(w2));
                    acc[d][3] = __hadd2(acc[d][3], u2h2(w3));
                }
                if (d >= 1 && d <= 4) {           // dx=1 -> pixel d-1 (shift 1 half)
                    uint s0 = (w0 >> 16) | (w1 << 16);
                    uint s1 = (w1 >> 16) | (w2 << 16);
                    uint s2 = (w2 >> 16) | (w3 << 16);
                    uint s3 = (w3 >> 16) | (w4 << 16);
                    acc[d-1][0] = __hadd2(acc[d-1][0], u2h2(s0));
                    acc[d-1][1] = __hadd2(acc[d-1][1], u2h2(s1));
                    acc[d-1][2] = __hadd2(acc[d-1][2], u2h2(s2));
                    acc[d-1][3] = __hadd2(acc[d-1][3], u2h2(s3));
                }
                if (d >= 2) {                     // dx=2 -> pixel d-2 (shift 1 uint)
                    acc[d-2][0] = __hadd2(acc[d-2][0], u2h2(w1));
                    acc[d-2][1] = __hadd2(acc[d-2][1], u2h2(w2));
                    acc[d-2][2] = __hadd2(acc[d-2][2], u2h2(w3));
                    acc[d-2][3] = __hadd2(acc[d-2][3], u2h2(w4));
                }
            }
        }
    }

    // purge pad-slot garbage (slots 46,47 of each jy row)
    if (vc6) {
#pragma unroll
        for (int p = 0; p < 4; p++) acc[p][3] = u2h2(0u);
    }

    // ---- phase A: per-pixel sum & sumsq of ds = k1 - 2*cs ----
#pragma unroll
    for (int p = 0; p < 4; p++) {
        float s1p = 0.f, s2p = 0.f;
#pragma unroll
        for (int k = 0; k < 4; k++) {
            float2 f = __half22float2(acc[p][k]);
            float d0 = k1v[2*k]   - 2.f * f.x;
            float d1 = k1v[2*k+1] - 2.f * f.y;
            s1p += d0 + d1;
            s2p = fmaf(d0, d0, fmaf(d1, d1, s2p));
        }
        red[p][t] = s1p;
        red[4 + p][t] = s2p;
    }
    __syncthreads();
    if (t < 128) {
        int v = t >> 4, sb = t & 15;
        float s = 0.f;
#pragma unroll
        for (int k = 0; k < 20; k++) s += red[v][sb + 16 * k];
#pragma unroll
        for (int o = 8; o > 0; o >>= 1) s += __shfl_down(s, o, 16);
        if (sb == 0) red[v][320] = s;
    }
    __syncthreads();
    float mu[4], isd[4];
#pragma unroll
    for (int p = 0; p < 4; p++) {
        float m = red[p][320] * (1.f / (float)CC);
        float ex2 = red[4 + p][320] * (1.f / (float)CC);
        mu[p] = m;
        isd[p] = rsqrtf(ex2 - m * m);
    }

    // ---- exp pass: pack unnormalized exp as bf16 pairs, accumulate es ----
    uint eb[4][4];
#pragma unroll
    for (int p = 0; p < 4; p++) {
        float es = 0.f;
#pragma unroll
        for (int k = 0; k < 4; k++) {
            float2 f = __half22float2(acc[p][k]);
            float d0 = k1v[2*k]   - 2.f * f.x;
            float d1 = k1v[2*k+1] - 2.f * f.y;
            if (k == 3 && vc6) { d0 = 1e9f; d1 = 1e9f; }   // pad slots -> ~e^-50 -> fp16 0
            float e0 = softexp(d0, mu[p], isd[p]);
            float e1 = softexp(d1, mu[p], isd[p]);
            es += e0 + e1;
            eb[p][k] = cvtpk_bf16(e0, e1);
        }
        red[p][t] = act ? es : 0.f;
    }
    __syncthreads();
    if (t < 64) {
        int v = t >> 4, sb = t & 15;
        float s = 0.f;
#pragma unroll
        for (int k = 0; k < 20; k++) s += red[v][sb + 16 * k];
#pragma unroll
        for (int o = 8; o > 0; o >>= 1) s += __shfl_down(s, o, 16);
        if (sb == 0) red[v][320] = s;
    }
    __syncthreads();

    // ---- normalize and store fp16 CA ----
    if (act) {
#pragma unroll
        for (int p = 0; p < 4; p++) {
            float iz = __builtin_amdgcn_rcpf(red[p][320]);
            uint o[4];
#pragma unroll
            for (int k = 0; k < 4; k++) {
                uint wv = eb[p][k];
                float lo = __uint_as_float(wv << 16) * iz;
                float hi = __uint_as_float(wv & 0xffff0000u) * iz;
                __half2 hh = __halves2half2(__float2half_rn(lo), __float2half_rn(hi));
                o[k] = *(uint*)&hh;
            }
            int pix = y * WW + x0 + p;
            ushort* wp = CA + ((size_t)b * HWp + pix) * (size_t)NSLOT + slot0;
            *(uint4*)wp = *(const uint4*)o;
        }
    }
}

// ---------- W = 9-point diagonal box-sum of CA field (fp16 in/out) ----------
// W[(y,x),(vy,vx)] = sum_{dy,dx} CA[(y+1-dy, x+1-dx), (vy-dy, vx-dx)]
// Masks: row (y+1-dy, x+1-dx) in 48^2; col vy-dy in [0,46); col-x underflow/pads are
// self-masking (CA slots 46,47 of every row are zero).
__global__ __launch_bounds__(320) void boxsumW(const ushort* __restrict__ CAu,
                                               ushort* __restrict__ Wout) {
    int i0 = blockIdx.x;
    int b = (i0 & 7) >> 1;
    int sub = ((i0 >> 3) << 1) | (i0 & 1);       // 0..575
    int y = sub / 12, xt = sub - y * 12;
    int x0 = xt * 4;

    int t = threadIdx.x;
    if (t >= 288) return;                        // 288 groups of 8 v-cols
    int vy = t / 6, vx0 = (t - vy * 6) * 8;

    __half2 acc[4][4];
#pragma unroll
    for (int p = 0; p < 4; p++)
#pragma unroll
        for (int k = 0; k < 4; k++) acc[p][k] = u2h2(0u);

#pragma unroll
    for (int dy = 0; dy < 3; dy++) {
        int yy = y + 1 - dy;
        int jyv = vy - dy;
        if (yy < 0 || yy >= 48 || jyv < 0 || jyv >= 46) continue;
        const ushort* rp = CAu + (size_t)b * HWp * (size_t)NSLOT
                         + (ptrdiff_t)((yy * 48 + x0 - 1) * NSLOT + jyv * 48 + vx0 - 2);
        uint4 W4[6]; uint W1[6];
#pragma unroll
        for (int d = 0; d < 6; d++) {
            int xp = x0 - 1 + d;
            if (xp >= 0 && xp < 48) {
                W4[d] = *(const uint4*)(rp + (size_t)d * NSLOT);
                W1[d] = *(const uint*)(rp + (size_t)d * NSLOT + 8);
            } else {
                W4[d] = make_uint4(0u, 0u, 0u, 0u); W1[d] = 0u;
            }
        }
#pragma unroll
        for (int d = 0; d < 6; d++) {
            uint w0 = W4[d].x, w1 = W4[d].y, w2 = W4[d].z, w3 = W4[d].w, w4 = W1[d];
            if (vx0 == 0) w0 = 0u;               // cols jx=-2,-1 invalid
            if (d < 4) {                          // dx=2 -> p=d, h[0..7]
                acc[d][0] = __hadd2(acc[d][0], u2h2(w0));
                acc[d][1] = __hadd2(acc[d][1], u2h2(w1));
                acc[d][2] = __hadd2(acc[d][2], u2h2(w2));
                acc[d][3] = __hadd2(acc[d][3], u2h2(w3));
            }
            if (d >= 1 && d <= 4) {               // dx=1 -> p=d-1, h[1..8]
                uint s0 = (w0 >> 16) | (w1 << 16);
                uint s1 = (w1 >> 16) | (w2 << 16);
                uint s2 = (w2 >> 16) | (w3 << 16);
                uint s3 = (w3 >> 16) | (w4 << 16);
                acc[d-1][0] = __hadd2(acc[d-1][0], u2h2(s0));
                acc[d-1][1] = __hadd2(acc[d-1][1], u2h2(s1));
                acc[d-1][2] = __hadd2(acc[d-1][2], u2h2(s2));
                acc[d-1][3] = __hadd2(acc[d-1][3], u2h2(s3));
            }
            if (d >= 2) {                         // dx=0 -> p=d-2, h[2..9]
                acc[d-2][0] = __hadd2(acc[d-2][0], u2h2(w1));
                acc[d-2][1] = __hadd2(acc[d-2][1], u2h2(w2));
                acc[d-2][2] = __hadd2(acc[d-2][2], u2h2(w3));
                acc[d-2][3] = __hadd2(acc[d-2][3], u2h2(w4));
            }
        }
    }

#pragma unroll
    for (int p = 0; p < 4; p++) {
        uint o[4];
#pragma unroll
        for (int k = 0; k < 4; k++) {
            __half2 h = acc[p][k];
            o[k] = *(uint*)&h;
        }
        size_t row = (size_t)b * HWp + (size_t)(y * 48 + x0 + p);
        *(uint4*)(Wout + row * QW + vy * 48 + vx0) = *(const uint4*)o;
    }
}

// ---------- gemm3: acl = W * bg^T  (M=2304/batch, N=64, K=2304, split-K=8) ----------
__global__ __launch_bounds__(256) void gemm3(const ushort* __restrict__ Wm,
                                             const ushort* __restrict__ bgT,
                                             float* __restrict__ aclp) {
    __shared__ ushort As[2 * 4096];
    __shared__ ushort Bs[2 * 2048];
    int i0 = blockIdx.x;                  // 576 = 18 mt x 4 b x 8 s
    int s = i0 & 7;                       // split pinned per XCD
    int b = (i0 >> 3) & 3;
    int mt = i0 >> 5;
    int m0 = mt * 128;
    int kb = s * 288, ke = kb + 288;
    const ushort* Ab = Wm + ((size_t)b * HWp + m0) * QW;
    const ushort* Bb = bgT + (size_t)b * 64 * QW;

    int tid = threadIdx.x;
    int l = tid & 63, w = tid >> 6;
    int quad = l >> 4, l15 = l & 15;
    int sw8 = (l15 >> 1) & 3;
    int wm = w * 32;
    int rowInC = l >> 2;
    int cSw = (l & 3) ^ ((l >> 3) & 3);

    float4v acc[2][4];
#pragma unroll
    for (int i = 0; i < 2; i++)
#pragma unroll
        for (int j = 0; j < 4; j++) acc[i][j] = (float4v){0.f, 0.f, 0.f, 0.f};

#pragma unroll
    for (int i = 0; i < 2; i++) {
        int rg = w * 2 + i;
        gld16(Ab + (size_t)(rg * 16 + rowInC) * QW + kb + cSw * 8, As + rg * 512);
    }
    gld16(Bb + (size_t)(w * 16 + rowInC) * QW + kb + cSw * 8, Bs + w * 512);

    int buf = 0;
    for (int k0 = kb; k0 < ke; k0 += 32) {
        __syncthreads();
        int nb = buf ^ 1;
        if (k0 + 32 < ke) {
#pragma unroll
            for (int i = 0; i < 2; i++) {
                int rg = w * 2 + i;
                gld16(Ab + (size_t)(rg * 16 + rowInC) * QW + (k0 + 32) + cSw * 8,
                      As + nb * 4096 + rg * 512);
            }
            gld16(Bb + (size_t)(w * 16 + rowInC) * QW + (k0 + 32) + cSw * 8,
                  Bs + nb * 2048 + w * 512);
        }
        const ushort* Ax = As + buf * 4096;
        const ushort* Bx = Bs + buf * 2048;
        half8 af[2], bf[4];
#pragma unroll
        for (int i = 0; i < 2; i++)
            af[i] = *(const half8*)&Ax[(wm + i * 16 + l15) * 32 + ((quad ^ sw8)) * 8];
#pragma unroll
        for (int j = 0; j < 4; j++)
            bf[j] = *(const half8*)&Bx[(j * 16 + l15) * 32 + ((quad ^ sw8)) * 8];
#pragma unroll
        for (int i = 0; i < 2; i++)
#pragma unroll
            for (int j = 0; j < 4; j++)
                acc[i][j] = __builtin_amdgcn_mfma_f32_16x16x32_f16(af[i], bf[j], acc[i][j], 0, 0, 0);
        buf = nb;
    }

    float* C = aclp + ((size_t)s * (BB * HWp) + (size_t)b * HWp) * 64;
#pragma unroll
    for (int i = 0; i < 2; i++)
#pragma unroll
        for (int j = 0; j < 4; j++)
#pragma unroll
            for (int r = 0; r < 4; r++) {
                int m = m0 + wm + i * 16 + quad * 4 + r;
                int n = j * 16 + l15;
                C[(size_t)m * 64 + n] = acc[i][j][r];
            }
}

// ---------- final: sum 8 split partials, ACL, concat, W2, ELU ----------
__global__ __launch_bounds__(256) void final_k2(const float* __restrict__ g,
                                                const float* __restrict__ mask,
                                                const float* __restrict__ aclp,
                                                const float* __restrict__ W2,
                                                const float* __restrict__ b2,
                                                float* __restrict__ out) {
    int w = threadIdx.x >> 6, d = threadIdx.x & 63;
    int pix = blockIdx.x * 4 + w;

    __shared__ float con1[4][128];
    float acl = 0.f;
    const float* ap = aclp + (size_t)pix * 64 + d;
#pragma unroll
    for (int s = 0; s < 8; s++) acl += ap[(size_t)s * (BB * HWp) * 64];

    float m = mask[pix];
    float gv = g[(size_t)pix * DD + d];
    float bgv = gv * m;
    float ACL = bgv + (acl / 9.f) * (1.f - m);
    con1[w][d] = gv;
    con1[w][64 + d] = ACL;
    __syncthreads();
    float accv = b2[d];
#pragma unroll 8
    for (int k = 0; k < 128; k++) accv = fmaf(con1[w][k], W2[k * 64 + d], accv);
    out[(size_t)pix * DD + d] = accv > 0.f ? accv : expm1f(accv);
}

extern "C" void kernel_launch(void* const* d_in, const int* in_sizes, int n_in,
                              void* d_out, int out_size, void* d_ws, size_t ws_size,
                              hipStream_t stream) {
    const float* g    = (const float*)d_in[0];
    const float* mask = (const float*)d_in[1];
    const float* W2   = (const float*)d_in[2];
    const float* b2   = (const float*)d_in[3];
    float* out = (float*)d_out;
    char* ws = (char*)d_ws;

    ushort* gpad  = (ushort*)(ws + OFFB_GPAD);
    ushort* bgpad = (ushort*)(ws + OFFB_BGPAD);
    float*  e     = (float*) (ws + OFFB_E);
    float*  k1d   = (float*) (ws + OFFB_K1D);
    ushort* bgT   = (ushort*)(ws + OFFB_BGT);
    __half* Qbuf  = (__half*)(ws + OFFB_Q);
    ushort* CA    = (ushort*)(ws + OFFB_S);
    ushort* Wbuf  = (ushort*)(ws + OFFB_W);
    float*  aclp  = (float*) (ws + OFFB_ACL);

    build_pads<<<BB * PP / 4, 256, 0, stream>>>(g, mask, gpad, bgpad, e);
    build_bgt_k1d<<<dim3(37, BB), 256, 0, stream>>>(bgpad, e, bgT, k1d);

    qgemm<<<1440, 256, 0, stream>>>(gpad, bgpad, Qbuf);
    qrowsoft3<<<BB * HWp / 4, 320, 0, stream>>>(Qbuf, k1d, CA);

    boxsumW<<<BB * HWp / 4, 320, 0, stream>>>(CA, Wbuf);
    gemm3<<<576, 256, 0, stream>>>(Wbuf, bgT, aclp);

    final_k2<<<BB * HWp / 4, 256, 0, stream>>>(g, mask, aclp, W2, b2, out);
}